// Round 1
// baseline (1623.697 us; speedup 1.0000x reference)
//
#include <hip/hip_runtime.h>

#define T_TOTAL 8192
#define DIN     64
#define UNITS   128
#define CHUNK   512
#define WARM    32
#define TW      16   // t-steps staged per LDS window

// Taylor-7 (odd) coefficients for sigmoid(z) - 0.5 = z*(c0 + c1 y + c2 y^2 + c3 y^3), y=z^2
#define SC0 (0.25f)
#define SC1 (-1.0f/48.0f)
#define SC2 (1.0f/480.0f)
#define SC3 (-17.0f/80640.0f)

__global__ __launch_bounds__(128, 2)
void ode_kernel(const float* __restrict__ gin,  // [64,8192,64]
                const float* __restrict__ gA,   // [128,64]
                const float* __restrict__ gsig, // [128,64]
                const float* __restrict__ gmu,  // [128,64]
                const float* __restrict__ gx0,  // [128]
                float* __restrict__ gout)       // [64,8192,128]
{
    const int u     = threadIdx.x;   // 0..127
    const int b     = blockIdx.y;    // 0..63
    const int chunk = blockIdx.x;    // 0..15

    __shared__ float  Als[DIN][UNITS];        // A transposed: [j][u]  (32 KB)
    __shared__ float4 ins4[TW * (DIN / 4)];   // staged inputs (4 KB)

    // ---- per-u tables into registers (const-indexed after unroll) ----
    float sg[DIN];   // sigma[u][j]
    float sh[DIN];   // sigma[u][j]*mu[u][j]
    float sumA = 0.0f;
    {
        const float4* s4 = reinterpret_cast<const float4*>(gsig + u * DIN);
        const float4* m4 = reinterpret_cast<const float4*>(gmu  + u * DIN);
        const float4* a4 = reinterpret_cast<const float4*>(gA   + u * DIN);
        #pragma unroll
        for (int k = 0; k < DIN / 4; ++k) {
            float4 s = s4[k], m = m4[k], a = a4[k];
            sg[4*k+0] = s.x; sg[4*k+1] = s.y; sg[4*k+2] = s.z; sg[4*k+3] = s.w;
            sh[4*k+0] = s.x * m.x; sh[4*k+1] = s.y * m.y;
            sh[4*k+2] = s.z * m.z; sh[4*k+3] = s.w * m.w;
            Als[4*k+0][u] = a.x; Als[4*k+1][u] = a.y;
            Als[4*k+2][u] = a.z; Als[4*k+3][u] = a.w;
            sumA += a.x + a.y + a.z + a.w;
        }
    }
    const float halfA = 0.5f * sumA;

    const float dtu = 0.1f / 3.0f;
    const float cb  = 1.0f - 33.0f * dtu;  // c = cb - dtu*q, with s0 = 32 + q

    const int tstore = chunk * CHUNK;
    const int tbegin = (chunk == 0) ? 0 : (tstore - WARM);
    const int tend   = tstore + CHUNK;

    float x = (chunk == 0) ? gx0[u] : 0.0f;

    for (int tw = tbegin; tw < tend; tw += TW) {
        __syncthreads();
        {   // stage TW*DIN floats = 256 float4 with 128 threads (2 each), coalesced
            const float4* src = reinterpret_cast<const float4*>(
                gin + ((size_t)b * T_TOTAL + tw) * DIN);
            ins4[threadIdx.x]       = src[threadIdx.x];
            ins4[threadIdx.x + 128] = src[threadIdx.x + 128];
        }
        __syncthreads();

        for (int tl = 0; tl < TW; ++tl) {
            const int t = tw + tl;
            float q0 = 0.f, q1 = 0.f, q2 = 0.f, q3 = 0.f;
            float r0 = 0.f, r1 = 0.f, r2 = 0.f, r3 = 0.f;

            #pragma unroll
            for (int jj = 0; jj < DIN / 4; ++jj) {
                float4 v = ins4[tl * (DIN / 4) + jj];  // broadcast read
                // 4 elements, j = 4*jj .. 4*jj+3
                {
                    const int j = 4 * jj + 0;
                    float z = fmaf(sg[j], v.x, -sh[j]);
                    z = fminf(1.3f, fmaxf(-1.3f, z));
                    float y = z * z;
                    float p = fmaf(fmaf(fmaf(SC3, y, SC2), y, SC1), y, SC0);
                    float w = z * p;               // f = 0.5 + w
                    q0 += w;
                    r0 = fmaf(w, Als[j][u], r0);
                }
                {
                    const int j = 4 * jj + 1;
                    float z = fmaf(sg[j], v.y, -sh[j]);
                    z = fminf(1.3f, fmaxf(-1.3f, z));
                    float y = z * z;
                    float p = fmaf(fmaf(fmaf(SC3, y, SC2), y, SC1), y, SC0);
                    float w = z * p;
                    q1 += w;
                    r1 = fmaf(w, Als[j][u], r1);
                }
                {
                    const int j = 4 * jj + 2;
                    float z = fmaf(sg[j], v.z, -sh[j]);
                    z = fminf(1.3f, fmaxf(-1.3f, z));
                    float y = z * z;
                    float p = fmaf(fmaf(fmaf(SC3, y, SC2), y, SC1), y, SC0);
                    float w = z * p;
                    q2 += w;
                    r2 = fmaf(w, Als[j][u], r2);
                }
                {
                    const int j = 4 * jj + 3;
                    float z = fmaf(sg[j], v.w, -sh[j]);
                    z = fminf(1.3f, fmaxf(-1.3f, z));
                    float y = z * z;
                    float p = fmaf(fmaf(fmaf(SC3, y, SC2), y, SC1), y, SC0);
                    float w = z * p;
                    q3 += w;
                    r3 = fmaf(w, Als[j][u], r3);
                }
            }

            const float q  = (q0 + q1) + (q2 + q3);   // s0 = 32 + q
            const float r  = (r0 + r1) + (r2 + r3);
            const float s1 = halfA + r;

            const float c  = fmaf(-dtu, q, cb);
            const float cc = c * c;
            const float e  = (dtu * s1) * (1.0f + c + cc);
            x = fmaf(cc * c, x, e);

            if (t >= tstore) {
                gout[((size_t)b * T_TOTAL + t) * UNITS + u] = x;
            }
        }
    }
}

extern "C" void kernel_launch(void* const* d_in, const int* in_sizes, int n_in,
                              void* d_out, int out_size, void* d_ws, size_t ws_size,
                              hipStream_t stream) {
    const float* gin  = (const float*)d_in[0];
    const float* gA   = (const float*)d_in[1];
    const float* gsig = (const float*)d_in[2];
    const float* gmu  = (const float*)d_in[3];
    const float* gx0  = (const float*)d_in[4];
    float* gout = (float*)d_out;

    dim3 grid(T_TOTAL / CHUNK, 64);  // 16 chunks x 64 batches = 1024 blocks
    dim3 block(128);
    hipLaunchKernelGGL(ode_kernel, grid, block, 0, stream,
                       gin, gA, gsig, gmu, gx0, gout);
}